// Round 4
// baseline (747.618 us; speedup 1.0000x reference)
//
#include <hip/hip_runtime.h>
#include <hip/hip_bf16.h>
#include <cstdint>
#include <cstddef>

// Problem constants (B*F tokens)
#define T_TOK 8192
#define DDIM  1024
#define HDIM  2048
#define NEXP  8
#define TOPK  2
#define KAUG  (3 * DDIM)   // split-bf16 router K

typedef short bf16x8 __attribute__((ext_vector_type(8)));
typedef float f32x4  __attribute__((ext_vector_type(4)));

__device__ __forceinline__ unsigned short f2bf(float f) {
  union { float f; unsigned u; } v; v.f = f;
  unsigned r = v.u + 0x7FFFu + ((v.u >> 16) & 1u);
  return (unsigned short)(r >> 16);
}
__device__ __forceinline__ float bf2f(unsigned short h) {
  union { unsigned u; float f; } v; v.u = ((unsigned)h) << 16;
  return v.f;
}
__device__ __forceinline__ float silu_fast(float v) {
  return v / (1.0f + __expf(-v));
}
__device__ __forceinline__ float silu_precise(float v) {
  return v / (1.0f + expf(-v));
}

// async global->LDS, 16B per lane; LDS dest is wave-uniform base + lane*16
__device__ __forceinline__ void gload16(const unsigned short* g, unsigned short* l) {
  __builtin_amdgcn_global_load_lds(
      (const __attribute__((address_space(1))) unsigned int*)g,
      (__attribute__((address_space(3))) unsigned int*)l,
      16, 0, 0);
}

// ---------------- conversion kernels ----------------
// x fp32 -> xaug = [hi | hi | lo] per row (K=3072); hi part doubles as expert A
__global__ void split_x_kernel(const float* __restrict__ in,
                               unsigned short* __restrict__ xaug, int n4) {
  int i = blockIdx.x * blockDim.x + threadIdx.x;
  if (i >= n4) return;
  float4 v = ((const float4*)in)[i];
  int t = i / (DDIM / 4);
  int kc = (i % (DDIM / 4)) * 4;
  float f[4] = {v.x, v.y, v.z, v.w};
  ushort4 hi, lo;
  unsigned short h[4], l[4];
#pragma unroll
  for (int j = 0; j < 4; j++) {
    h[j] = f2bf(f[j]);
    l[j] = f2bf(f[j] - bf2f(h[j]));
  }
  hi.x = h[0]; hi.y = h[1]; hi.z = h[2]; hi.w = h[3];
  lo.x = l[0]; lo.y = l[1]; lo.z = l[2]; lo.w = l[3];
  *(ushort4*)&xaug[(size_t)t * KAUG + kc] = hi;
  *(ushort4*)&xaug[(size_t)t * KAUG + DDIM + kc] = hi;
  *(ushort4*)&xaug[(size_t)t * KAUG + 2 * DDIM + kc] = lo;
}

// rw1 [k][n] fp32 -> waug [n][3072] = [whi | wlo | whi]
__global__ __launch_bounds__(256) void split_w_kernel(
    const float* __restrict__ in, unsigned short* __restrict__ waug) {
  __shared__ float tile[32][33];
  int c0 = blockIdx.x * 32, r0 = blockIdx.y * 32;
  int tx = threadIdx.x & 31, ty = threadIdx.x >> 5;
#pragma unroll
  for (int i = 0; i < 32; i += 8)
    tile[ty + i][tx] = in[(size_t)(r0 + ty + i) * DDIM + (c0 + tx)];
  __syncthreads();
#pragma unroll
  for (int i = 0; i < 32; i += 8) {
    float v = tile[tx][ty + i];          // in[r0+tx][c0+ty+i]
    unsigned short h = f2bf(v);
    unsigned short l = f2bf(v - bf2f(h));
    int n = c0 + ty + i, k = r0 + tx;
    waug[(size_t)n * KAUG + k] = h;
    waug[(size_t)n * KAUG + DDIM + k] = l;
    waug[(size_t)n * KAUG + 2 * DDIM + k] = h;
  }
}

// in: [z][R][C] fp32 -> out: [z][C][R] bf16
__global__ __launch_bounds__(256) void transpose_conv_kernel(
    const float* __restrict__ in, unsigned short* __restrict__ out, int R, int C) {
  __shared__ float tile[32][33];
  const int z = blockIdx.z;
  const float* src = in + (size_t)z * R * C;
  unsigned short* dst = out + (size_t)z * R * C;
  int c0 = blockIdx.x * 32, r0 = blockIdx.y * 32;
  int tx = threadIdx.x & 31, ty = threadIdx.x >> 5;
#pragma unroll
  for (int i = 0; i < 32; i += 8)
    tile[ty + i][tx] = src[(size_t)(r0 + ty + i) * C + (c0 + tx)];
  __syncthreads();
#pragma unroll
  for (int i = 0; i < 32; i += 8)
    dst[(size_t)(c0 + ty + i) * R + (r0 + tx)] = f2bf(tile[tx][ty + i]);
}

__global__ void zero_small_kernel(int* __restrict__ counts, int* __restrict__ cursors) {
  int i = threadIdx.x;
  if (i < NEXP) { counts[i] = 0; cursors[i] = 0; }
}

// ---------------- MFMA GEMM v4: 128x256 tile, BK=64, 3-buffer ring ----------
// 8 waves (2m x 4n), wave tile 64x64. LDS = 3 x (A 16KB + B 32KB) = 144KB.
// Verified round-1 layout: 128B LDS rows, chunk ^= (row&7) XOR swizzle via
// pre-swizzled global source (0 bank conflicts measured).
// Ring ledger (race-free):
//   during tile t: buf[t%3]=t (reading), buf[(t+1)%3]=t+1 (landed),
//   buf[(t+2)%3]=t+2 (in flight). Tile t+3's 6 loads issue after barrier B3
//   (all waves' reads of buf[t%3] done) into buf[t%3].
//   Steady-state wait: vmcnt(12) at tile start (t+1,t+2 stay in flight) —
//   never 0 until the final tile. Each load has ~2 K-tiles to land.
// Per K-tile, 2 phases (template rhythm): {8x ds_read_b128; lgkmcnt(0);
//   setprio(1); 16 MFMA; setprio(0); barrier}.
// EPI=0: router1  -> outF = silu(acc+bias)            (A dense)
// EPI=1: expert1  -> outBf = bf16(silu(acc+bias))     (A gathered by toks)
// EPI=2: expert2  -> outBf = bf16(acc+bias)           (A = packed ehb)
template <int EPI>
__global__ __launch_bounds__(512, 2) void gemm_mfma4(
    const unsigned short* __restrict__ Abase,
    const unsigned short* __restrict__ Btbase,  // [z][N][KD] bf16 (pre-transposed)
    const float* __restrict__ bias,             // [z][N]
    float* __restrict__ outF,
    unsigned short* __restrict__ outBf,
    const int* __restrict__ toks,
    const int* __restrict__ offs, const int* __restrict__ cnts,
    int N, int KD, int Astride, int numE, int nTiles, int mCap) {
  constexpr int BUFB = 49152;   // A 16KB + B 32KB per ring slot
  extern __shared__ char sm[];  // 3 slots

  const int id = blockIdx.x;
  const int e = id % numE;
  const int r = id / numE;
  const int n0 = (r % nTiles) * 256;
  const int mb = r / nTiles;

  int ne = T_TOK, off = 0;
  if (EPI != 0) { ne = cnts[e]; off = offs[e]; }

  const unsigned short* Bt = Btbase + (size_t)e * N * KD;
  const unsigned short* A = (EPI == 2) ? (Abase + (size_t)off * Astride) : Abase;

  const int tid = threadIdx.x;
  const int lane = tid & 63, wid = tid >> 6;
  const int l16 = lane & 15, quad = lane >> 4;
  const int wm = wid >> 2, wn = wid & 3;   // 2 x 4 waves; wave tile 64 x 64

  // staging map: per 8KB round (64 rows x 128B), thread tid covers bytes tid*16
  const int rStage = tid >> 3;                       // 0..63
  const int cS8 = ((tid & 7) ^ (rStage & 7)) * 8;    // pre-swizzled source chunk
  const int ldsW = wid << 10;                        // wave-uniform dest part

  const int NT = KD / 64;
  const int mStride = mCap * 128;

  // frag-read byte offsets: row*128 + ((chunk)^(row&7))*16, row&7 == l16&7
  const int sw = l16 & 7;
  const int cOff0 = (quad ^ sw) << 4;          // k-slice 0 (chunks 0..3)
  const int cOff1 = ((quad + 4) ^ sw) << 4;    // k-slice 1 (chunks 4..7)
  const int aFragB = (wm * 64 + l16) << 7;             // + mi*(16<<7)
  const int bFragB = 16384 + ((wn * 64 + l16) << 7);   // + ni*(16<<7)

  const unsigned short* bP[4];
#pragma unroll
  for (int p = 0; p < 4; p++)
    bP[p] = Bt + (size_t)(n0 + p * 64 + rStage) * KD + cS8;

  for (int m0 = mb * 128; m0 < ne; m0 += mStride) {
    const unsigned short* aP[2];
#pragma unroll
    for (int p = 0; p < 2; p++) {
      int row = m0 + p * 64 + rStage;
      int idx;
      if (EPI == 1) idx = toks[off + min(row, ne - 1)];
      else if (EPI == 2) idx = min(row, ne - 1);
      else idx = row;
      aP[p] = A + (size_t)idx * Astride + cS8;
    }

    f32x4 acc[4][4];
    const f32x4 zf = {0.f, 0.f, 0.f, 0.f};
#pragma unroll
    for (int mi = 0; mi < 4; mi++)
#pragma unroll
      for (int ni = 0; ni < 4; ni++) acc[mi][ni] = zf;

    // stage K-tile t (k = t*64) into ring slot b: 6 loads (2 A + 4 B rounds)
    auto stage = [&](int t, int b) {
      char* base = sm + b * BUFB + ldsW;
      gload16(aP[0] + t * 64, (unsigned short*)(base));
      gload16(aP[1] + t * 64, (unsigned short*)(base + 8192));
      gload16(bP[0] + t * 64, (unsigned short*)(base + 16384));
      gload16(bP[1] + t * 64, (unsigned short*)(base + 24576));
      gload16(bP[2] + t * 64, (unsigned short*)(base + 32768));
      gload16(bP[3] + t * 64, (unsigned short*)(base + 40960));
    };

    // prologue: fill the ring (NT >= 3 for all our shapes)
    stage(0, 0);
    stage(1, 1);
    stage(2, 2);

    for (int t = 0; t < NT; ++t) {
      const char* base = sm + (t % 3) * BUFB;
      // B1: tile t's loads landed (own vmcnt + barrier => all waves').
      // s_waitcnt builtin needs an IMMEDIATE constant -> literal branch ladder.
      if (t + 2 < NT)      __builtin_amdgcn_s_waitcnt(0x0F70 | 12); // vmcnt(12)
      else if (t + 1 < NT) __builtin_amdgcn_s_waitcnt(0x0F70 | 6);  // vmcnt(6)
      else                 __builtin_amdgcn_s_waitcnt(0x0F70);      // vmcnt(0)
      __builtin_amdgcn_s_barrier();
      __builtin_amdgcn_sched_barrier(0);

      bf16x8 av[4], bv[4];
      // ---- phase 0 (k-slice 0) ----
#pragma unroll
      for (int mi = 0; mi < 4; mi++)
        av[mi] = *(const bf16x8*)(base + aFragB + (mi << 11) + cOff0);
#pragma unroll
      for (int ni = 0; ni < 4; ni++)
        bv[ni] = *(const bf16x8*)(base + bFragB + (ni << 11) + cOff0);
      __builtin_amdgcn_s_waitcnt(0xC07F);   // lgkmcnt(0)
      __builtin_amdgcn_sched_barrier(0);
      __builtin_amdgcn_s_setprio(1);
#pragma unroll
      for (int mi = 0; mi < 4; mi++)
#pragma unroll
        for (int ni = 0; ni < 4; ni++)
          acc[mi][ni] = __builtin_amdgcn_mfma_f32_16x16x32_bf16(
              av[mi], bv[ni], acc[mi][ni], 0, 0, 0);
      __builtin_amdgcn_s_setprio(0);
      __builtin_amdgcn_s_barrier();         // B2: phase sync

      // ---- phase 1 (k-slice 1) ----
#pragma unroll
      for (int mi = 0; mi < 4; mi++)
        av[mi] = *(const bf16x8*)(base + aFragB + (mi << 11) + cOff1);
#pragma unroll
      for (int ni = 0; ni < 4; ni++)
        bv[ni] = *(const bf16x8*)(base + bFragB + (ni << 11) + cOff1);
      __builtin_amdgcn_s_waitcnt(0xC07F);   // lgkmcnt(0): reads retired
      __builtin_amdgcn_s_barrier();         // B3: ALL waves done with buf[t%3]
      __builtin_amdgcn_sched_barrier(0);
      if (t + 3 < NT) stage(t + 3, t % 3);  // overwrite-safe; ~2 tiles to land
      __builtin_amdgcn_s_setprio(1);
#pragma unroll
      for (int mi = 0; mi < 4; mi++)
#pragma unroll
        for (int ni = 0; ni < 4; ni++)
          acc[mi][ni] = __builtin_amdgcn_mfma_f32_16x16x32_bf16(
              av[mi], bv[ni], acc[mi][ni], 0, 0, 0);
      __builtin_amdgcn_s_setprio(0);
    }

    // epilogue (C/D layout: col = lane&15, row = quad*4 + rr)
    float bv4[4];
#pragma unroll
    for (int ni = 0; ni < 4; ni++)
      bv4[ni] = bias[(size_t)e * N + n0 + wn * 64 + ni * 16 + l16];
#pragma unroll
    for (int mi = 0; mi < 4; mi++) {
      const int prow = m0 + wm * 64 + mi * 16 + quad * 4;
#pragma unroll
      for (int rr = 0; rr < 4; rr++) {
        const int p = prow + rr;
        if (EPI != 0 && p >= ne) continue;
#pragma unroll
        for (int ni = 0; ni < 4; ni++) {
          const int col = n0 + wn * 64 + ni * 16 + l16;
          float v = acc[mi][ni][rr] + bv4[ni];
          if (EPI == 0) {
            outF[(size_t)p * N + col] = silu_precise(v);
          } else if (EPI == 1) {
            outBf[(size_t)(off + p) * N + col] = f2bf(silu_fast(v));
          } else {
            outBf[(size_t)(off + p) * N + col] = f2bf(v);
          }
        }
      }
    }
  }
}

// ---------------- router second layer: logits = rh @ rw2 + rb2 ----------------
__global__ __launch_bounds__(256) void router2_kernel(
    const float* __restrict__ rh, const float* __restrict__ rw2,
    const float* __restrict__ rb2, float* __restrict__ logits) {
  int t = blockIdx.x * 4 + (threadIdx.x >> 6);
  int lane = threadIdx.x & 63;
  const float* row = rh + (size_t)t * DDIM;
  float acc[NEXP];
#pragma unroll
  for (int e = 0; e < NEXP; e++) acc[e] = 0.f;
  for (int k = lane; k < DDIM; k += 64) {
    float v = row[k];
    const float* w = rw2 + (size_t)k * NEXP;
#pragma unroll
    for (int e = 0; e < NEXP; e++) acc[e] += v * w[e];
  }
#pragma unroll
  for (int e = 0; e < NEXP; e++) {
#pragma unroll
    for (int off = 32; off > 0; off >>= 1) acc[e] += __shfl_xor(acc[e], off, 64);
  }
#pragma unroll
  for (int e = 0; e < NEXP; e++)
    if (lane == e) logits[(size_t)t * NEXP + e] = acc[e] + rb2[e];
}

// ---------------- top-2 + softmax + counts ----------------
__global__ void topk_kernel(const float* __restrict__ logits,
                            int* __restrict__ idx2, float* __restrict__ w2arr,
                            int* __restrict__ counts) {
  int t = blockIdx.x * blockDim.x + threadIdx.x;
  if (t >= T_TOK) return;
  float l[NEXP];
#pragma unroll
  for (int e = 0; e < NEXP; e++) l[e] = logits[(size_t)t * NEXP + e];
  int i1 = 0; float v1 = l[0];
#pragma unroll
  for (int e = 1; e < NEXP; e++)
    if (l[e] > v1) { v1 = l[e]; i1 = e; }
  int i2 = -1; float v2 = -3.4e38f;
#pragma unroll
  for (int e = 0; e < NEXP; e++)
    if (e != i1 && l[e] > v2) { v2 = l[e]; i2 = e; }
  float ex = expf(v2 - v1);
  float wa = 1.f / (1.f + ex);
  float wb = ex / (1.f + ex);
  idx2[t * 2] = i1; idx2[t * 2 + 1] = i2;
  w2arr[t * 2] = wa; w2arr[t * 2 + 1] = wb;
  atomicAdd(&counts[i1], 1);
  atomicAdd(&counts[i2], 1);
}

__global__ void prefix_kernel(const int* __restrict__ counts, int* __restrict__ offs) {
  if (threadIdx.x == 0 && blockIdx.x == 0) {
    int s = 0;
    for (int e = 0; e < NEXP; e++) { offs[e] = s; s += counts[e]; }
  }
}

__global__ void scatter_kernel(const int* __restrict__ idx2,
                               const int* __restrict__ offs, int* __restrict__ cursors,
                               int* __restrict__ toks, int* __restrict__ posArr) {
  int t = blockIdx.x * blockDim.x + threadIdx.x;
  if (t >= T_TOK) return;
#pragma unroll
  for (int j = 0; j < TOPK; j++) {
    int e = idx2[t * 2 + j];
    int pos = atomicAdd(&cursors[e], 1);
    int s = offs[e] + pos;
    toks[s] = t;
    posArr[t * 2 + j] = s;
  }
}

// ---------------- final combine: y = x + w0*eo[s0] + w1*eo[s1] ----------------
__global__ __launch_bounds__(256) void combine_kernel(
    const float* __restrict__ x, const unsigned short* __restrict__ eo,
    const int* __restrict__ posArr, const float* __restrict__ w2arr,
    float* __restrict__ y) {
  const int t = blockIdx.x;
  const int d = threadIdx.x * 4;
  const int s0 = posArr[t * 2], s1 = posArr[t * 2 + 1];
  const float w0 = w2arr[t * 2], w1 = w2arr[t * 2 + 1];
  float4 xv = *(const float4*)&x[(size_t)t * DDIM + d];
  ushort4 a = *(const ushort4*)&eo[(size_t)s0 * DDIM + d];
  ushort4 b = *(const ushort4*)&eo[(size_t)s1 * DDIM + d];
  float4 o;
  o.x = xv.x + w0 * bf2f(a.x) + w1 * bf2f(b.x);
  o.y = xv.y + w0 * bf2f(a.y) + w1 * bf2f(b.y);
  o.z = xv.z + w0 * bf2f(a.z) + w1 * bf2f(b.z);
  o.w = xv.w + w0 * bf2f(a.w) + w1 * bf2f(b.w);
  *(float4*)&y[(size_t)t * DDIM + d] = o;
}

// ---------------- launch ----------------
extern "C" void kernel_launch(void* const* d_in, const int* in_sizes, int n_in,
                              void* d_out, int out_size, void* d_ws, size_t ws_size,
                              hipStream_t stream) {
  (void)in_sizes; (void)n_in; (void)out_size; (void)ws_size;
  const float* x   = (const float*)d_in[0];
  const float* rw1 = (const float*)d_in[1];
  const float* rb1 = (const float*)d_in[2];
  const float* rw2 = (const float*)d_in[3];
  const float* rb2 = (const float*)d_in[4];
  const float* ew1 = (const float*)d_in[5];
  const float* eb1 = (const float*)d_in[6];
  const float* ew2 = (const float*)d_in[7];
  const float* eb2 = (const float*)d_in[8];
  float* y = (float*)d_out;

  char* ws = (char*)d_ws;
  size_t o = 0;
  auto alloc = [&](size_t bytes) {
    size_t r = o;
    o += (bytes + 255) & ~(size_t)255;
    return r;
  };
  unsigned short* xaug  = (unsigned short*)(ws + alloc((size_t)T_TOK * KAUG * 2));
  unsigned short* waug  = (unsigned short*)(ws + alloc((size_t)DDIM * KAUG * 2));
  unsigned short* ew1t  = (unsigned short*)(ws + alloc((size_t)NEXP * HDIM * DDIM * 2));
  unsigned short* ew2t  = (unsigned short*)(ws + alloc((size_t)NEXP * DDIM * HDIM * 2));
  float*          rh    = (float*)(ws + alloc((size_t)T_TOK * DDIM * 4));
  float*          logits= (float*)(ws + alloc((size_t)T_TOK * NEXP * 4));
  int*            idx2  = (int*)(ws + alloc((size_t)T_TOK * 2 * 4));
  float*          w2    = (float*)(ws + alloc((size_t)T_TOK * 2 * 4));
  int*            toks  = (int*)(ws + alloc((size_t)T_TOK * TOPK * 4));
  int*            posArr= (int*)(ws + alloc((size_t)T_TOK * TOPK * 4));
  int*            counts= (int*)(ws + alloc(256));
  int*            cursors=(int*)(ws + alloc(256));
  int*            offs  = (int*)(ws + alloc(256));
  unsigned short* ehb   = (unsigned short*)(ws + alloc((size_t)T_TOK * TOPK * HDIM * 2));
  unsigned short* eo    = (unsigned short*)(ws + alloc((size_t)T_TOK * TOPK * DDIM * 2));

  constexpr int LDS_SZ = 3 * 49152;   // 147456: 3-slot ring (A 16K + B 32K)
  static bool s_attr = false;
  if (!s_attr) {
    (void)hipFuncSetAttribute((const void*)gemm_mfma4<0>,
                              hipFuncAttributeMaxDynamicSharedMemorySize, LDS_SZ);
    (void)hipFuncSetAttribute((const void*)gemm_mfma4<1>,
                              hipFuncAttributeMaxDynamicSharedMemorySize, LDS_SZ);
    (void)hipFuncSetAttribute((const void*)gemm_mfma4<2>,
                              hipFuncAttributeMaxDynamicSharedMemorySize, LDS_SZ);
    s_attr = true;
  }

  zero_small_kernel<<<1, 64, 0, stream>>>(counts, cursors);

  const int n4 = T_TOK * DDIM / 4;
  split_x_kernel<<<(n4 + 255) / 256, 256, 0, stream>>>(x, xaug, n4);
  split_w_kernel<<<dim3(DDIM / 32, DDIM / 32), 256, 0, stream>>>(rw1, waug);
  transpose_conv_kernel<<<dim3(HDIM / 32, DDIM / 32, NEXP), 256, 0, stream>>>(ew1, ew1t, DDIM, HDIM);
  transpose_conv_kernel<<<dim3(DDIM / 32, HDIM / 32, NEXP), 256, 0, stream>>>(ew2, ew2t, HDIM, DDIM);

  // router layer 1 (split-bf16, K=3072, NT=48): rh = silu(x @ rw1 + rb1)
  // 128x256 tiles: numE=1, nTiles=4, mCap=64 -> grid 256 (1 block/CU)
  gemm_mfma4<0><<<256, 512, LDS_SZ, stream>>>(
      xaug, waug, rb1, rh, nullptr, nullptr, nullptr, nullptr,
      DDIM, KAUG, KAUG, 1, 4, 64);
  router2_kernel<<<T_TOK / 4, 256, 0, stream>>>(rh, rw2, rb2, logits);
  topk_kernel<<<T_TOK / 256, 256, 0, stream>>>(logits, idx2, w2, counts);
  prefix_kernel<<<1, 64, 0, stream>>>(counts, offs);
  scatter_kernel<<<T_TOK / 256, 256, 0, stream>>>(idx2, offs, cursors, toks, posArr);

  // expert layer 1: ehb = silu(gather(xaug.hi) @ ew1[e] + eb1[e])  (bf16)
  // NT=16: numE=8 (XCD-aligned), nTiles=8, mCap=16 -> grid 1024
  gemm_mfma4<1><<<8 * 8 * 16, 512, LDS_SZ, stream>>>(
      xaug, ew1t, eb1, nullptr, ehb, toks, offs, counts,
      HDIM, DDIM, KAUG, NEXP, 8, 16);
  // expert layer 2: eo = ehb @ ew2[e] + eb2[e]  (bf16, packed; weights in combine)
  // NT=32: numE=8, nTiles=4, mCap=16 -> grid 512
  gemm_mfma4<2><<<8 * 4 * 16, 512, LDS_SZ, stream>>>(
      ehb, ew2t, eb2, nullptr, eo, nullptr, offs, counts,
      DDIM, HDIM, HDIM, NEXP, 4, 16);
  // y = x + w0*eo[s0] + w1*eo[s1]
  combine_kernel<<<T_TOK, 256, 0, stream>>>(x, eo, posArr, w2, y);
}

// Round 6
// 741.956 us; speedup vs baseline: 1.0076x; 1.0076x over previous
//
#include <hip/hip_runtime.h>
#include <hip/hip_bf16.h>
#include <cstdint>
#include <cstddef>

// Problem constants (B*F tokens)
#define T_TOK 8192
#define DDIM  1024
#define HDIM  2048
#define NEXP  8
#define TOPK  2
#define KAUG  (3 * DDIM)   // split-bf16 router K

typedef short bf16x8 __attribute__((ext_vector_type(8)));
typedef float f32x4  __attribute__((ext_vector_type(4)));

__device__ __forceinline__ unsigned short f2bf(float f) {
  union { float f; unsigned u; } v; v.f = f;
  unsigned r = v.u + 0x7FFFu + ((v.u >> 16) & 1u);
  return (unsigned short)(r >> 16);
}
__device__ __forceinline__ float bf2f(unsigned short h) {
  union { unsigned u; float f; } v; v.u = ((unsigned)h) << 16;
  return v.f;
}
__device__ __forceinline__ float silu_fast(float v) {
  return v / (1.0f + __expf(-v));
}
__device__ __forceinline__ float silu_precise(float v) {
  return v / (1.0f + expf(-v));
}

// async global->LDS, 16B per lane; LDS dest is wave-uniform base + lane*16
__device__ __forceinline__ void gload16(const unsigned short* g, unsigned short* l) {
  __builtin_amdgcn_global_load_lds(
      (const __attribute__((address_space(1))) unsigned int*)g,
      (__attribute__((address_space(3))) unsigned int*)l,
      16, 0, 0);
}

// ---------------- conversion kernels ----------------
// x fp32 -> xaug = [hi | hi | lo] per row (K=3072); hi part doubles as expert A
__global__ void split_x_kernel(const float* __restrict__ in,
                               unsigned short* __restrict__ xaug, int n4) {
  int i = blockIdx.x * blockDim.x + threadIdx.x;
  if (i >= n4) return;
  float4 v = ((const float4*)in)[i];
  int t = i / (DDIM / 4);
  int kc = (i % (DDIM / 4)) * 4;
  float f[4] = {v.x, v.y, v.z, v.w};
  ushort4 hi, lo;
  unsigned short h[4], l[4];
#pragma unroll
  for (int j = 0; j < 4; j++) {
    h[j] = f2bf(f[j]);
    l[j] = f2bf(f[j] - bf2f(h[j]));
  }
  hi.x = h[0]; hi.y = h[1]; hi.z = h[2]; hi.w = h[3];
  lo.x = l[0]; lo.y = l[1]; lo.z = l[2]; lo.w = l[3];
  *(ushort4*)&xaug[(size_t)t * KAUG + kc] = hi;
  *(ushort4*)&xaug[(size_t)t * KAUG + DDIM + kc] = hi;
  *(ushort4*)&xaug[(size_t)t * KAUG + 2 * DDIM + kc] = lo;
}

// rw1 [k][n] fp32 -> waug [n][3072] = [whi | wlo | whi]
__global__ __launch_bounds__(256) void split_w_kernel(
    const float* __restrict__ in, unsigned short* __restrict__ waug) {
  __shared__ float tile[32][33];
  int c0 = blockIdx.x * 32, r0 = blockIdx.y * 32;
  int tx = threadIdx.x & 31, ty = threadIdx.x >> 5;
#pragma unroll
  for (int i = 0; i < 32; i += 8)
    tile[ty + i][tx] = in[(size_t)(r0 + ty + i) * DDIM + (c0 + tx)];
  __syncthreads();
#pragma unroll
  for (int i = 0; i < 32; i += 8) {
    float v = tile[tx][ty + i];          // in[r0+tx][c0+ty+i]
    unsigned short h = f2bf(v);
    unsigned short l = f2bf(v - bf2f(h));
    int n = c0 + ty + i, k = r0 + tx;
    waug[(size_t)n * KAUG + k] = h;
    waug[(size_t)n * KAUG + DDIM + k] = l;
    waug[(size_t)n * KAUG + 2 * DDIM + k] = h;
  }
}

// in: [z][R][C] fp32 -> out: [z][C][R] bf16
__global__ __launch_bounds__(256) void transpose_conv_kernel(
    const float* __restrict__ in, unsigned short* __restrict__ out, int R, int C) {
  __shared__ float tile[32][33];
  const int z = blockIdx.z;
  const float* src = in + (size_t)z * R * C;
  unsigned short* dst = out + (size_t)z * R * C;
  int c0 = blockIdx.x * 32, r0 = blockIdx.y * 32;
  int tx = threadIdx.x & 31, ty = threadIdx.x >> 5;
#pragma unroll
  for (int i = 0; i < 32; i += 8)
    tile[ty + i][tx] = src[(size_t)(r0 + ty + i) * C + (c0 + tx)];
  __syncthreads();
#pragma unroll
  for (int i = 0; i < 32; i += 8)
    dst[(size_t)(c0 + ty + i) * R + (r0 + tx)] = f2bf(tile[tx][ty + i]);
}

__global__ void zero_small_kernel(int* __restrict__ counts, int* __restrict__ cursors) {
  int i = threadIdx.x;
  if (i < NEXP) { counts[i] = 0; cursors[i] = 0; }
}

// ---------------- MFMA GEMM v5b: m201 8-phase port. 256x256, BK=64 ---------
// 8 waves (2m x 4n), wave tile 128x64. LDS 128KB: A [2dbuf][256][64]b16 @0,
// B same @65536. 128B rows, chunk^=(row&7) swizzle via pre-swizzled global
// source (0 conflicts, verified r1/r4).
// Region read-map per K-tile (buffer t&1):
//   A-half0 (rows 0..127)   read ph1 (mi0..3, wm0) AND ph3 (mi4..7, wm0)
//   A-half1 (rows 128..255) read ph1 (wm1) AND ph3 (wm1)   -> A free after ph3
//   B-half0 (rows 0..127)   read ph1 bR0 + ph2 bR1 (wn0,1) -> free after ph2
//   B-half1 (rows 128..255) read ph1 bR0 + ph2 bR1 (wn2,3) -> free after ph2
// Stage placement (write-after-read safe; r5 had stA0 in ph2 = RACE):
//   ph1: stB1(t+1) (opposite-parity buffer)
//   ph2: (none)
//   ph3: stB0(t+2) (B retired at ph2 lgkm(0)+barrier)
//   ph4: stA0(t+2) + stA1(t+2) (A retired at ph3 lgkm(0)+barrier)
// vmcnt ledger: prologue stages t0 (8) + {A0,B0,A1}(1) (6), vmcnt(4)/vmcnt(6);
// steady-state invariant entering tile t: 6 outstanding = {A0,B0,A1}(t+1);
// end-of-tile vmcnt(6) retires exactly tile t+1's 8 loads; vmcnt(0) only at
// t=NT-2; no wait at t=NT-1.
// EPI=0: router1  -> outF = silu(acc+bias)            (A dense)
// EPI=1: expert1  -> outBf = bf16(silu(acc+bias))     (A gathered by toks)
// EPI=2: expert2  -> outBf = bf16(acc+bias)           (A = packed ehb)
template <int EPI>
__global__ __launch_bounds__(512, 2) void gemm8p(
    const unsigned short* __restrict__ Abase,
    const unsigned short* __restrict__ Btbase,  // [z][N][KD] bf16 (pre-transposed)
    const float* __restrict__ bias,             // [z][N]
    float* __restrict__ outF,
    unsigned short* __restrict__ outBf,
    const int* __restrict__ toks,
    const int* __restrict__ offs, const int* __restrict__ cnts,
    int N, int KD, int Astride, int numE, int nTiles, int mCap) {
  extern __shared__ char sm[];

  const int id = blockIdx.x;
  const int e = id % numE;
  const int r = id / numE;
  const int n0 = (r % nTiles) * 256;
  const int mb = r / nTiles;

  int ne = T_TOK, off = 0;
  if (EPI != 0) { ne = cnts[e]; off = offs[e]; }

  const unsigned short* Bt = Btbase + (size_t)e * N * KD;
  const unsigned short* A = (EPI == 2) ? (Abase + (size_t)off * Astride) : Abase;

  const int tid = threadIdx.x;
  const int lane = tid & 63, wid = tid >> 6;
  const int l16 = lane & 15, quad = lane >> 4;
  const int wm = wid >> 2, wn = wid & 3;   // 2 x 4 waves; wave tile 128 x 64

  // staging map: per 8KB sub-op (64 rows x 128B), thread covers bytes tid*16
  const int rStage = tid >> 3;                       // 0..63
  const int cS8 = ((tid & 7) ^ (rStage & 7)) * 8;    // pre-swizzled source chunk
  const int ldsW = wid << 10;                        // wave-uniform dest part

  const int NT = KD / 64;
  const int mStride = mCap * 256;

  // frag-read byte offsets: row*128 + (chunk ^ (row&7))*16, row&7 == l16&7
  const int sw = l16 & 7;
  const int cOff0 = (quad ^ sw) << 4;          // k-slice 0
  const int cOff1 = ((quad + 4) ^ sw) << 4;    // k-slice 1
  const int aRowB = (wm * 128 + l16) << 7;     // + mi*2048
  const int bRowB = (wn * 64 + l16) << 7;      // + ni*2048

  const unsigned short* bP[4];
#pragma unroll
  for (int p = 0; p < 4; p++)
    bP[p] = Bt + (size_t)(n0 + p * 64 + rStage) * KD + cS8;

  for (int m0 = mb * 256; m0 < ne; m0 += mStride) {
    const unsigned short* aP[4];
#pragma unroll
    for (int p = 0; p < 4; p++) {
      int row = m0 + p * 64 + rStage;
      int idx;
      if (EPI == 1) idx = toks[off + min(row, ne - 1)];
      else if (EPI == 2) idx = min(row, ne - 1);
      else idx = row;
      aP[p] = A + (size_t)idx * Astride + cS8;
    }

    // half-tile stages (2 gloads each, all pointer indices compile-time)
    auto stA0 = [&](int t) { char* b = sm + (t & 1) * 32768 + ldsW; int kb = t * 64;
      gload16(aP[0] + kb, (unsigned short*)b);
      gload16(aP[1] + kb, (unsigned short*)(b + 8192)); };
    auto stA1 = [&](int t) { char* b = sm + (t & 1) * 32768 + 16384 + ldsW; int kb = t * 64;
      gload16(aP[2] + kb, (unsigned short*)b);
      gload16(aP[3] + kb, (unsigned short*)(b + 8192)); };
    auto stB0 = [&](int t) { char* b = sm + 65536 + (t & 1) * 32768 + ldsW; int kb = t * 64;
      gload16(bP[0] + kb, (unsigned short*)b);
      gload16(bP[1] + kb, (unsigned short*)(b + 8192)); };
    auto stB1 = [&](int t) { char* b = sm + 65536 + (t & 1) * 32768 + 16384 + ldsW; int kb = t * 64;
      gload16(bP[2] + kb, (unsigned short*)b);
      gload16(bP[3] + kb, (unsigned short*)(b + 8192)); };

    f32x4 acc[8][4];
    const f32x4 zf = {0.f, 0.f, 0.f, 0.f};
#pragma unroll
    for (int mi = 0; mi < 8; mi++)
#pragma unroll
      for (int ni = 0; ni < 4; ni++) acc[mi][ni] = zf;

    // prologue: tile0 complete + tile1 {A0,B0,A1} (NT >= 2 always here)
    stA0(0); stB0(0); stA1(0); stB1(0);
    __builtin_amdgcn_s_waitcnt(0x0F74);  // vmcnt(4)
    stA0(1); stB0(1); stA1(1);
    __builtin_amdgcn_s_waitcnt(0x0F76);  // vmcnt(6): tile0 fully landed
    __builtin_amdgcn_s_barrier();

    for (int t = 0; t < NT; ++t) {
      const char* bA = sm + (t & 1) * 32768;
      const char* bB = bA + 65536;
      bf16x8 aR[8], bR0[4], bR1[4];

      // ---- phase 1: Am0 + Bn0 (12 reads); stage B1(t+1); MFMA m0..3 x n0..1
#pragma unroll
      for (int mi = 0; mi < 4; mi++) {
        aR[mi * 2]     = *(const bf16x8*)(bA + aRowB + mi * 2048 + cOff0);
        aR[mi * 2 + 1] = *(const bf16x8*)(bA + aRowB + mi * 2048 + cOff1);
      }
#pragma unroll
      for (int ni = 0; ni < 2; ni++) {
        bR0[ni * 2]     = *(const bf16x8*)(bB + bRowB + ni * 2048 + cOff0);
        bR0[ni * 2 + 1] = *(const bf16x8*)(bB + bRowB + ni * 2048 + cOff1);
      }
      if (t + 1 < NT) stB1(t + 1);
      __builtin_amdgcn_s_waitcnt(0xC87F);  // lgkmcnt(8)
      __builtin_amdgcn_s_barrier();
      __builtin_amdgcn_s_waitcnt(0xC07F);  // lgkmcnt(0)
      __builtin_amdgcn_sched_barrier(0);
      __builtin_amdgcn_s_setprio(1);
#pragma unroll
      for (int mi = 0; mi < 4; mi++)
#pragma unroll
        for (int ni = 0; ni < 2; ni++) {
          acc[mi][ni] = __builtin_amdgcn_mfma_f32_16x16x32_bf16(
              aR[mi * 2], bR0[ni * 2], acc[mi][ni], 0, 0, 0);
          acc[mi][ni] = __builtin_amdgcn_mfma_f32_16x16x32_bf16(
              aR[mi * 2 + 1], bR0[ni * 2 + 1], acc[mi][ni], 0, 0, 0);
        }
      __builtin_amdgcn_s_setprio(0);
      __builtin_amdgcn_s_barrier();

      // ---- phase 2: Bn1 (4 reads); NO stage; MFMA m0..3 x n2..3 ----
#pragma unroll
      for (int ni = 0; ni < 2; ni++) {
        bR1[ni * 2]     = *(const bf16x8*)(bB + bRowB + (ni + 2) * 2048 + cOff0);
        bR1[ni * 2 + 1] = *(const bf16x8*)(bB + bRowB + (ni + 2) * 2048 + cOff1);
      }
      __builtin_amdgcn_s_barrier();
      __builtin_amdgcn_s_waitcnt(0xC07F);
      __builtin_amdgcn_sched_barrier(0);
      __builtin_amdgcn_s_setprio(1);
#pragma unroll
      for (int mi = 0; mi < 4; mi++)
#pragma unroll
        for (int ni = 0; ni < 2; ni++) {
          acc[mi][ni + 2] = __builtin_amdgcn_mfma_f32_16x16x32_bf16(
              aR[mi * 2], bR1[ni * 2], acc[mi][ni + 2], 0, 0, 0);
          acc[mi][ni + 2] = __builtin_amdgcn_mfma_f32_16x16x32_bf16(
              aR[mi * 2 + 1], bR1[ni * 2 + 1], acc[mi][ni + 2], 0, 0, 0);
        }
      __builtin_amdgcn_s_setprio(0);
      __builtin_amdgcn_s_barrier();

      // ---- phase 3: Am1 (8 reads); stage B0(t+2); MFMA m4..7 x n2..3 ----
#pragma unroll
      for (int mi = 0; mi < 4; mi++) {
        aR[mi * 2]     = *(const bf16x8*)(bA + aRowB + (mi + 4) * 2048 + cOff0);
        aR[mi * 2 + 1] = *(const bf16x8*)(bA + aRowB + (mi + 4) * 2048 + cOff1);
      }
      if (t + 2 < NT) stB0(t + 2);
      __builtin_amdgcn_s_barrier();
      __builtin_amdgcn_s_waitcnt(0xC07F);
      __builtin_amdgcn_sched_barrier(0);
      __builtin_amdgcn_s_setprio(1);
#pragma unroll
      for (int mi = 0; mi < 4; mi++)
#pragma unroll
        for (int ni = 0; ni < 2; ni++) {
          acc[mi + 4][ni + 2] = __builtin_amdgcn_mfma_f32_16x16x32_bf16(
              aR[mi * 2], bR1[ni * 2], acc[mi + 4][ni + 2], 0, 0, 0);
          acc[mi + 4][ni + 2] = __builtin_amdgcn_mfma_f32_16x16x32_bf16(
              aR[mi * 2 + 1], bR1[ni * 2 + 1], acc[mi + 4][ni + 2], 0, 0, 0);
        }
      __builtin_amdgcn_s_setprio(0);
      __builtin_amdgcn_s_barrier();

      // ---- phase 4: no reads (Bn0, Am1 kept); stage A0+A1(t+2);
      //      MFMA m4..7 x n0..1 ----
      if (t + 2 < NT) { stA0(t + 2); stA1(t + 2); }
      __builtin_amdgcn_s_barrier();
      __builtin_amdgcn_sched_barrier(0);
      __builtin_amdgcn_s_setprio(1);
#pragma unroll
      for (int mi = 0; mi < 4; mi++)
#pragma unroll
        for (int ni = 0; ni < 2; ni++) {
          acc[mi + 4][ni] = __builtin_amdgcn_mfma_f32_16x16x32_bf16(
              aR[mi * 2], bR0[ni * 2], acc[mi + 4][ni], 0, 0, 0);
          acc[mi + 4][ni] = __builtin_amdgcn_mfma_f32_16x16x32_bf16(
              aR[mi * 2 + 1], bR0[ni * 2 + 1], acc[mi + 4][ni], 0, 0, 0);
        }
      __builtin_amdgcn_s_setprio(0);
      if (t + 2 < NT)      __builtin_amdgcn_s_waitcnt(0x0F76);  // vmcnt(6)
      else if (t + 1 < NT) __builtin_amdgcn_s_waitcnt(0x0F70);  // vmcnt(0)
      __builtin_amdgcn_s_barrier();
    }

    // epilogue (C/D layout: col = lane&15, row = quad*4 + rr)
    float bv4[4];
#pragma unroll
    for (int ni = 0; ni < 4; ni++)
      bv4[ni] = bias[(size_t)e * N + n0 + wn * 64 + ni * 16 + l16];
#pragma unroll
    for (int mi = 0; mi < 8; mi++) {
      const int prow = m0 + wm * 128 + mi * 16 + quad * 4;
#pragma unroll
      for (int rr = 0; rr < 4; rr++) {
        const int p = prow + rr;
        if (EPI != 0 && p >= ne) continue;
#pragma unroll
        for (int ni = 0; ni < 4; ni++) {
          const int col = n0 + wn * 64 + ni * 16 + l16;
          float v = acc[mi][ni][rr] + bv4[ni];
          if (EPI == 0) {
            outF[(size_t)p * N + col] = silu_precise(v);
          } else if (EPI == 1) {
            outBf[(size_t)(off + p) * N + col] = f2bf(silu_fast(v));
          } else {
            outBf[(size_t)(off + p) * N + col] = f2bf(v);
          }
        }
      }
    }
  }
}

// ---------------- router second layer: logits = rh @ rw2 + rb2 ----------------
__global__ __launch_bounds__(256) void router2_kernel(
    const float* __restrict__ rh, const float* __restrict__ rw2,
    const float* __restrict__ rb2, float* __restrict__ logits) {
  int t = blockIdx.x * 4 + (threadIdx.x >> 6);
  int lane = threadIdx.x & 63;
  const float* row = rh + (size_t)t * DDIM;
  float acc[NEXP];
#pragma unroll
  for (int e = 0; e < NEXP; e++) acc[e] = 0.f;
  for (int k = lane; k < DDIM; k += 64) {
    float v = row[k];
    const float* w = rw2 + (size_t)k * NEXP;
#pragma unroll
    for (int e = 0; e < NEXP; e++) acc[e] += v * w[e];
  }
#pragma unroll
  for (int e = 0; e < NEXP; e++) {
#pragma unroll
    for (int off = 32; off > 0; off >>= 1) acc[e] += __shfl_xor(acc[e], off, 64);
  }
#pragma unroll
  for (int e = 0; e < NEXP; e++)
    if (lane == e) logits[(size_t)t * NEXP + e] = acc[e] + rb2[e];
}

// ---------------- top-2 + softmax + counts ----------------
__global__ void topk_kernel(const float* __restrict__ logits,
                            int* __restrict__ idx2, float* __restrict__ w2arr,
                            int* __restrict__ counts) {
  int t = blockIdx.x * blockDim.x + threadIdx.x;
  if (t >= T_TOK) return;
  float l[NEXP];
#pragma unroll
  for (int e = 0; e < NEXP; e++) l[e] = logits[(size_t)t * NEXP + e];
  int i1 = 0; float v1 = l[0];
#pragma unroll
  for (int e = 1; e < NEXP; e++)
    if (l[e] > v1) { v1 = l[e]; i1 = e; }
  int i2 = -1; float v2 = -3.4e38f;
#pragma unroll
  for (int e = 0; e < NEXP; e++)
    if (e != i1 && l[e] > v2) { v2 = l[e]; i2 = e; }
  float ex = expf(v2 - v1);
  float wa = 1.f / (1.f + ex);
  float wb = ex / (1.f + ex);
  idx2[t * 2] = i1; idx2[t * 2 + 1] = i2;
  w2arr[t * 2] = wa; w2arr[t * 2 + 1] = wb;
  atomicAdd(&counts[i1], 1);
  atomicAdd(&counts[i2], 1);
}

__global__ void prefix_kernel(const int* __restrict__ counts, int* __restrict__ offs) {
  if (threadIdx.x == 0 && blockIdx.x == 0) {
    int s = 0;
    for (int e = 0; e < NEXP; e++) { offs[e] = s; s += counts[e]; }
  }
}

__global__ void scatter_kernel(const int* __restrict__ idx2,
                               const int* __restrict__ offs, int* __restrict__ cursors,
                               int* __restrict__ toks, int* __restrict__ posArr) {
  int t = blockIdx.x * blockDim.x + threadIdx.x;
  if (t >= T_TOK) return;
#pragma unroll
  for (int j = 0; j < TOPK; j++) {
    int e = idx2[t * 2 + j];
    int pos = atomicAdd(&cursors[e], 1);
    int s = offs[e] + pos;
    toks[s] = t;
    posArr[t * 2 + j] = s;
  }
}

// ---------------- final combine: y = x + w0*eo[s0] + w1*eo[s1] ----------------
__global__ __launch_bounds__(256) void combine_kernel(
    const float* __restrict__ x, const unsigned short* __restrict__ eo,
    const int* __restrict__ posArr, const float* __restrict__ w2arr,
    float* __restrict__ y) {
  const int t = blockIdx.x;
  const int d = threadIdx.x * 4;
  const int s0 = posArr[t * 2], s1 = posArr[t * 2 + 1];
  const float w0 = w2arr[t * 2], w1 = w2arr[t * 2 + 1];
  float4 xv = *(const float4*)&x[(size_t)t * DDIM + d];
  ushort4 a = *(const ushort4*)&eo[(size_t)s0 * DDIM + d];
  ushort4 b = *(const ushort4*)&eo[(size_t)s1 * DDIM + d];
  float4 o;
  o.x = xv.x + w0 * bf2f(a.x) + w1 * bf2f(b.x);
  o.y = xv.y + w0 * bf2f(a.y) + w1 * bf2f(b.y);
  o.z = xv.z + w0 * bf2f(a.z) + w1 * bf2f(b.z);
  o.w = xv.w + w0 * bf2f(a.w) + w1 * bf2f(b.w);
  *(float4*)&y[(size_t)t * DDIM + d] = o;
}

// ---------------- launch ----------------
extern "C" void kernel_launch(void* const* d_in, const int* in_sizes, int n_in,
                              void* d_out, int out_size, void* d_ws, size_t ws_size,
                              hipStream_t stream) {
  (void)in_sizes; (void)n_in; (void)out_size; (void)ws_size;
  const float* x   = (const float*)d_in[0];
  const float* rw1 = (const float*)d_in[1];
  const float* rb1 = (const float*)d_in[2];
  const float* rw2 = (const float*)d_in[3];
  const float* rb2 = (const float*)d_in[4];
  const float* ew1 = (const float*)d_in[5];
  const float* eb1 = (const float*)d_in[6];
  const float* ew2 = (const float*)d_in[7];
  const float* eb2 = (const float*)d_in[8];
  float* y = (float*)d_out;

  char* ws = (char*)d_ws;
  size_t o = 0;
  auto alloc = [&](size_t bytes) {
    size_t r = o;
    o += (bytes + 255) & ~(size_t)255;
    return r;
  };
  unsigned short* xaug  = (unsigned short*)(ws + alloc((size_t)T_TOK * KAUG * 2));
  unsigned short* waug  = (unsigned short*)(ws + alloc((size_t)DDIM * KAUG * 2));
  unsigned short* ew1t  = (unsigned short*)(ws + alloc((size_t)NEXP * HDIM * DDIM * 2));
  unsigned short* ew2t  = (unsigned short*)(ws + alloc((size_t)NEXP * DDIM * HDIM * 2));
  float*          rh    = (float*)(ws + alloc((size_t)T_TOK * DDIM * 4));
  float*          logits= (float*)(ws + alloc((size_t)T_TOK * NEXP * 4));
  int*            idx2  = (int*)(ws + alloc((size_t)T_TOK * 2 * 4));
  float*          w2    = (float*)(ws + alloc((size_t)T_TOK * 2 * 4));
  int*            toks  = (int*)(ws + alloc((size_t)T_TOK * TOPK * 4));
  int*            posArr= (int*)(ws + alloc((size_t)T_TOK * TOPK * 4));
  int*            counts= (int*)(ws + alloc(256));
  int*            cursors=(int*)(ws + alloc(256));
  int*            offs  = (int*)(ws + alloc(256));
  unsigned short* ehb   = (unsigned short*)(ws + alloc((size_t)T_TOK * TOPK * HDIM * 2));
  unsigned short* eo    = (unsigned short*)(ws + alloc((size_t)T_TOK * TOPK * DDIM * 2));

  constexpr int LDS_SZ = 131072;   // A 2x32KB + B 2x32KB
  static bool s_attr = false;
  if (!s_attr) {
    (void)hipFuncSetAttribute((const void*)gemm8p<0>,
                              hipFuncAttributeMaxDynamicSharedMemorySize, LDS_SZ);
    (void)hipFuncSetAttribute((const void*)gemm8p<1>,
                              hipFuncAttributeMaxDynamicSharedMemorySize, LDS_SZ);
    (void)hipFuncSetAttribute((const void*)gemm8p<2>,
                              hipFuncAttributeMaxDynamicSharedMemorySize, LDS_SZ);
    s_attr = true;
  }

  zero_small_kernel<<<1, 64, 0, stream>>>(counts, cursors);

  const int n4 = T_TOK * DDIM / 4;
  split_x_kernel<<<(n4 + 255) / 256, 256, 0, stream>>>(x, xaug, n4);
  split_w_kernel<<<dim3(DDIM / 32, DDIM / 32), 256, 0, stream>>>(rw1, waug);
  transpose_conv_kernel<<<dim3(HDIM / 32, DDIM / 32, NEXP), 256, 0, stream>>>(ew1, ew1t, DDIM, HDIM);
  transpose_conv_kernel<<<dim3(DDIM / 32, HDIM / 32, NEXP), 256, 0, stream>>>(ew2, ew2t, HDIM, DDIM);

  // router layer 1 (split-bf16, K=3072, NT=48): rh = silu(x @ rw1 + rb1)
  // 256x256 tiles: numE=1, nTiles=4, mCap=32 -> grid 128, 1 m-iter
  gemm8p<0><<<128, 512, LDS_SZ, stream>>>(
      xaug, waug, rb1, rh, nullptr, nullptr, nullptr, nullptr,
      DDIM, KAUG, KAUG, 1, 4, 32);
  router2_kernel<<<T_TOK / 4, 256, 0, stream>>>(rh, rw2, rb2, logits);
  topk_kernel<<<T_TOK / 256, 256, 0, stream>>>(logits, idx2, w2, counts);
  prefix_kernel<<<1, 64, 0, stream>>>(counts, offs);
  scatter_kernel<<<T_TOK / 256, 256, 0, stream>>>(idx2, offs, cursors, toks, posArr);

  // expert layer 1: ehb = silu(gather(xaug.hi) @ ew1[e] + eb1[e])  (bf16)
  // NT=16: numE=8 (XCD), nTiles=8, mCap=4 -> grid 256, ~2 m-iters/block
  gemm8p<1><<<8 * 8 * 4, 512, LDS_SZ, stream>>>(
      xaug, ew1t, eb1, nullptr, ehb, toks, offs, counts,
      HDIM, DDIM, KAUG, NEXP, 8, 4);
  // expert layer 2: eo = ehb @ ew2[e] + eb2[e]  (bf16, packed; weights in combine)
  // NT=32: numE=8, nTiles=4, mCap=8 -> grid 256, 1-2 m-iters/block
  gemm8p<2><<<8 * 4 * 8, 512, LDS_SZ, stream>>>(
      ehb, ew2t, eb2, nullptr, eo, nullptr, offs, counts,
      DDIM, HDIM, HDIM, NEXP, 4, 8);
  // y = x + w0*eo[s0] + w1*eo[s1]
  combine_kernel<<<T_TOK, 256, 0, stream>>>(x, eo, posArr, w2, y);
}

// Round 7
// 694.054 us; speedup vs baseline: 1.0772x; 1.0690x over previous
//
#include <hip/hip_runtime.h>
#include <hip/hip_bf16.h>
#include <cstdint>
#include <cstddef>

// Problem constants (B*F tokens)
#define T_TOK 8192
#define DDIM  1024
#define HDIM  2048
#define NEXP  8
#define TOPK  2
#define KAUG  (3 * DDIM)   // split-bf16 router K

typedef short bf16x8 __attribute__((ext_vector_type(8)));
typedef float f32x4  __attribute__((ext_vector_type(4)));

__device__ __forceinline__ unsigned short f2bf(float f) {
  union { float f; unsigned u; } v; v.f = f;
  unsigned r = v.u + 0x7FFFu + ((v.u >> 16) & 1u);
  return (unsigned short)(r >> 16);
}
__device__ __forceinline__ float bf2f(unsigned short h) {
  union { unsigned u; float f; } v; v.u = ((unsigned)h) << 16;
  return v.f;
}
__device__ __forceinline__ float silu_fast(float v) {
  return v / (1.0f + __expf(-v));
}
__device__ __forceinline__ float silu_precise(float v) {
  return v / (1.0f + expf(-v));
}

// async global->LDS, 16B per lane; LDS dest is wave-uniform base + lane*16
__device__ __forceinline__ void gload16(const unsigned short* g, unsigned short* l) {
  __builtin_amdgcn_global_load_lds(
      (const __attribute__((address_space(1))) unsigned int*)g,
      (__attribute__((address_space(3))) unsigned int*)l,
      16, 0, 0);
}

// ---------------- conversion kernels ----------------
// x fp32 -> xaug = [hi | hi | lo] per row (K=3072); hi part doubles as expert A
__global__ void split_x_kernel(const float* __restrict__ in,
                               unsigned short* __restrict__ xaug, int n4) {
  int i = blockIdx.x * blockDim.x + threadIdx.x;
  if (i >= n4) return;
  float4 v = ((const float4*)in)[i];
  int t = i / (DDIM / 4);
  int kc = (i % (DDIM / 4)) * 4;
  float f[4] = {v.x, v.y, v.z, v.w};
  ushort4 hi, lo;
  unsigned short h[4], l[4];
#pragma unroll
  for (int j = 0; j < 4; j++) {
    h[j] = f2bf(f[j]);
    l[j] = f2bf(f[j] - bf2f(h[j]));
  }
  hi.x = h[0]; hi.y = h[1]; hi.z = h[2]; hi.w = h[3];
  lo.x = l[0]; lo.y = l[1]; lo.z = l[2]; lo.w = l[3];
  *(ushort4*)&xaug[(size_t)t * KAUG + kc] = hi;
  *(ushort4*)&xaug[(size_t)t * KAUG + DDIM + kc] = hi;
  *(ushort4*)&xaug[(size_t)t * KAUG + 2 * DDIM + kc] = lo;
}

// rw1 [k][n] fp32 -> waug [n][3072] = [whi | wlo | whi]
__global__ __launch_bounds__(256) void split_w_kernel(
    const float* __restrict__ in, unsigned short* __restrict__ waug) {
  __shared__ float tile[32][33];
  int c0 = blockIdx.x * 32, r0 = blockIdx.y * 32;
  int tx = threadIdx.x & 31, ty = threadIdx.x >> 5;
#pragma unroll
  for (int i = 0; i < 32; i += 8)
    tile[ty + i][tx] = in[(size_t)(r0 + ty + i) * DDIM + (c0 + tx)];
  __syncthreads();
#pragma unroll
  for (int i = 0; i < 32; i += 8) {
    float v = tile[tx][ty + i];          // in[r0+tx][c0+ty+i]
    unsigned short h = f2bf(v);
    unsigned short l = f2bf(v - bf2f(h));
    int n = c0 + ty + i, k = r0 + tx;
    waug[(size_t)n * KAUG + k] = h;
    waug[(size_t)n * KAUG + DDIM + k] = l;
    waug[(size_t)n * KAUG + 2 * DDIM + k] = h;
  }
}

// in: [z][R][C] fp32 -> out: [z][C][R] bf16
__global__ __launch_bounds__(256) void transpose_conv_kernel(
    const float* __restrict__ in, unsigned short* __restrict__ out, int R, int C) {
  __shared__ float tile[32][33];
  const int z = blockIdx.z;
  const float* src = in + (size_t)z * R * C;
  unsigned short* dst = out + (size_t)z * R * C;
  int c0 = blockIdx.x * 32, r0 = blockIdx.y * 32;
  int tx = threadIdx.x & 31, ty = threadIdx.x >> 5;
#pragma unroll
  for (int i = 0; i < 32; i += 8)
    tile[ty + i][tx] = src[(size_t)(r0 + ty + i) * C + (c0 + tx)];
  __syncthreads();
#pragma unroll
  for (int i = 0; i < 32; i += 8)
    dst[(size_t)(c0 + ty + i) * R + (r0 + tx)] = f2bf(tile[tx][ty + i]);
}

__global__ void zero_small_kernel(int* __restrict__ counts, int* __restrict__ cursors) {
  int i = threadIdx.x;
  if (i < NEXP) { counts[i] = 0; cursors[i] = 0; }
}

// ---------------- MFMA GEMM v6: 128x128 tile, BK=64, 2 blocks/CU -----------
// Diagnosis r0-r6: all 1-block/CU designs land at 14-19% MfmaUtil with ALL
// pipes idle -> latency/occupancy-bound (playbook: smaller tiles, bigger grid).
// This round: 4 waves (2x2, wave tile 64x64), LDS 64KB (A 2x16K + B 2x16K)
// -> 2 resident blocks/CU with INDEPENDENT barriers; grids 512-2048 blocks
// (XCD-aligned, up to 8 blocks/CU queued). Inter-block overlap hides the
// stage/barrier drain (m114 mechanism) instead of intra-block scheduling.
// Loop rhythm = round-1's session-best: stage(t+1) -> vmcnt(8 counted) ->
// barrier -> 16 ds_read_b128 -> 32 MFMA (setprio) -> barrier.
// LDS layout: 128B rows, chunk ^= (row&7) XOR swizzle via pre-swizzled global
// source (0 bank conflicts, verified r1/r4/r6).
// EPI=0: router1  -> outF = silu(acc+bias)            (A dense)
// EPI=1: expert1  -> outBf = bf16(silu(acc+bias))     (A gathered by toks)
// EPI=2: expert2  -> outBf = bf16(acc+bias)           (A = packed ehb)
template <int EPI>
__global__ __launch_bounds__(256) void gemm_s(
    const unsigned short* __restrict__ Abase,
    const unsigned short* __restrict__ Btbase,  // [z][N][KD] bf16 (pre-transposed)
    const float* __restrict__ bias,             // [z][N]
    float* __restrict__ outF,
    unsigned short* __restrict__ outBf,
    const int* __restrict__ toks,
    const int* __restrict__ offs, const int* __restrict__ cnts,
    int N, int KD, int Astride, int numE, int nTiles, int mCap) {
  extern __shared__ char sm[];   // 2 bufs x 32KB: [buf][A 16K | B 16K]

  const int id = blockIdx.x;
  const int e = id % numE;
  const int r = id / numE;
  const int n0 = (r % nTiles) * 128;
  const int mb = r / nTiles;

  int ne = T_TOK, off = 0;
  if (EPI != 0) { ne = cnts[e]; off = offs[e]; }

  const unsigned short* Bt = Btbase + (size_t)e * N * KD;
  const unsigned short* A = (EPI == 2) ? (Abase + (size_t)off * Astride) : Abase;

  const int tid = threadIdx.x;
  const int lane = tid & 63, wid = tid >> 6;   // 4 waves
  const int l16 = lane & 15, quad = lane >> 4;
  const int wm = wid >> 1, wn = wid & 1;       // 2x2; wave tile 64x64

  // staging: per operand 4 rounds of 32 rows x 128B; thread covers 16B
  // round p covers rows p*32 + (tid>>3); chunk slot tid&7 (linear dest),
  // source chunk pre-swizzled so LDS slot c holds global chunk c^(row&7)
  const int rStage = tid >> 3;                       // 0..31
  const int cS8 = ((tid & 7) ^ (rStage & 7)) * 8;    // pre-swizzled src chunk
  const int ldsW = wid << 10;                        // wave-uniform dest part

  const int NT = KD / 64;
  const int mStride = mCap * 128;

  // frag-read byte offsets: row*128 + (chunk ^ (row&7))*16, row&7 == l16&7
  const int sw = l16 & 7;
  const int cOff0 = (quad ^ sw) << 4;          // k-slice 0
  const int cOff1 = ((quad + 4) ^ sw) << 4;    // k-slice 1
  const int aRowB = (wm * 64 + l16) << 7;              // + mi*2048
  const int bRowB = 16384 + ((wn * 64 + l16) << 7);    // + ni*2048

  const unsigned short* bP[4];
#pragma unroll
  for (int p = 0; p < 4; p++)
    bP[p] = Bt + (size_t)(n0 + p * 32 + rStage) * KD + cS8;

  for (int m0 = mb * 128; m0 < ne; m0 += mStride) {
    const unsigned short* aP[4];
#pragma unroll
    for (int p = 0; p < 4; p++) {
      int row = m0 + p * 32 + rStage;
      int idx;
      if (EPI == 1) idx = toks[off + min(row, ne - 1)];
      else if (EPI == 2) idx = min(row, ne - 1);
      else idx = row;
      aP[p] = A + (size_t)idx * Astride + cS8;
    }

    f32x4 acc[4][4];
    const f32x4 zf = {0.f, 0.f, 0.f, 0.f};
#pragma unroll
    for (int mi = 0; mi < 4; mi++)
#pragma unroll
      for (int ni = 0; ni < 4; ni++) acc[mi][ni] = zf;

    // stage K-tile t into buffer b: 8 gloads/thread (4 A rounds + 4 B rounds)
    auto stage = [&](int t, int b) {
      char* base = sm + b * 32768 + ldsW;
      const int kb = t * 64;
#pragma unroll
      for (int p = 0; p < 4; p++) {
        gload16(aP[p] + kb, (unsigned short*)(base + p * 4096));
        gload16(bP[p] + kb, (unsigned short*)(base + 16384 + p * 4096));
      }
    };

    stage(0, 0);

    for (int t = 0; t < NT; ++t) {
      if (t + 1 < NT) {
        stage(t + 1, (t + 1) & 1);
        __builtin_amdgcn_s_waitcnt(0x0F78);  // vmcnt(8): tile t landed
      } else {
        __builtin_amdgcn_s_waitcnt(0x0F70);  // vmcnt(0)
      }
      __builtin_amdgcn_s_barrier();

      const char* base = sm + (t & 1) * 32768;
      bf16x8 av[4], bv[4];
      // ---- k-slice 0 ----
#pragma unroll
      for (int mi = 0; mi < 4; mi++)
        av[mi] = *(const bf16x8*)(base + aRowB + mi * 2048 + cOff0);
#pragma unroll
      for (int ni = 0; ni < 4; ni++)
        bv[ni] = *(const bf16x8*)(base + bRowB + ni * 2048 + cOff0);
      __builtin_amdgcn_s_setprio(1);
#pragma unroll
      for (int mi = 0; mi < 4; mi++)
#pragma unroll
        for (int ni = 0; ni < 4; ni++)
          acc[mi][ni] = __builtin_amdgcn_mfma_f32_16x16x32_bf16(
              av[mi], bv[ni], acc[mi][ni], 0, 0, 0);
      __builtin_amdgcn_s_setprio(0);
      // ---- k-slice 1 ----
#pragma unroll
      for (int mi = 0; mi < 4; mi++)
        av[mi] = *(const bf16x8*)(base + aRowB + mi * 2048 + cOff1);
#pragma unroll
      for (int ni = 0; ni < 4; ni++)
        bv[ni] = *(const bf16x8*)(base + bRowB + ni * 2048 + cOff1);
      __builtin_amdgcn_s_setprio(1);
#pragma unroll
      for (int mi = 0; mi < 4; mi++)
#pragma unroll
        for (int ni = 0; ni < 4; ni++)
          acc[mi][ni] = __builtin_amdgcn_mfma_f32_16x16x32_bf16(
              av[mi], bv[ni], acc[mi][ni], 0, 0, 0);
      __builtin_amdgcn_s_setprio(0);
      __builtin_amdgcn_s_barrier();   // all reads of buf(t) consumed
    }

    // epilogue (C/D layout: col = lane&15, row = quad*4 + rr)
    float bv4[4];
#pragma unroll
    for (int ni = 0; ni < 4; ni++)
      bv4[ni] = bias[(size_t)e * N + n0 + wn * 64 + ni * 16 + l16];
#pragma unroll
    for (int mi = 0; mi < 4; mi++) {
      const int prow = m0 + wm * 64 + mi * 16 + quad * 4;
#pragma unroll
      for (int rr = 0; rr < 4; rr++) {
        const int p = prow + rr;
        if (EPI != 0 && p >= ne) continue;
#pragma unroll
        for (int ni = 0; ni < 4; ni++) {
          const int col = n0 + wn * 64 + ni * 16 + l16;
          float v = acc[mi][ni][rr] + bv4[ni];
          if (EPI == 0) {
            outF[(size_t)p * N + col] = silu_precise(v);
          } else if (EPI == 1) {
            outBf[(size_t)(off + p) * N + col] = f2bf(silu_fast(v));
          } else {
            outBf[(size_t)(off + p) * N + col] = f2bf(v);
          }
        }
      }
    }
  }
}

// ---------------- router second layer: logits = rh @ rw2 + rb2 ----------------
__global__ __launch_bounds__(256) void router2_kernel(
    const float* __restrict__ rh, const float* __restrict__ rw2,
    const float* __restrict__ rb2, float* __restrict__ logits) {
  int t = blockIdx.x * 4 + (threadIdx.x >> 6);
  int lane = threadIdx.x & 63;
  const float* row = rh + (size_t)t * DDIM;
  float acc[NEXP];
#pragma unroll
  for (int e = 0; e < NEXP; e++) acc[e] = 0.f;
  for (int k = lane; k < DDIM; k += 64) {
    float v = row[k];
    const float* w = rw2 + (size_t)k * NEXP;
#pragma unroll
    for (int e = 0; e < NEXP; e++) acc[e] += v * w[e];
  }
#pragma unroll
  for (int e = 0; e < NEXP; e++) {
#pragma unroll
    for (int off = 32; off > 0; off >>= 1) acc[e] += __shfl_xor(acc[e], off, 64);
  }
#pragma unroll
  for (int e = 0; e < NEXP; e++)
    if (lane == e) logits[(size_t)t * NEXP + e] = acc[e] + rb2[e];
}

// ---------------- top-2 + softmax + counts ----------------
__global__ void topk_kernel(const float* __restrict__ logits,
                            int* __restrict__ idx2, float* __restrict__ w2arr,
                            int* __restrict__ counts) {
  int t = blockIdx.x * blockDim.x + threadIdx.x;
  if (t >= T_TOK) return;
  float l[NEXP];
#pragma unroll
  for (int e = 0; e < NEXP; e++) l[e] = logits[(size_t)t * NEXP + e];
  int i1 = 0; float v1 = l[0];
#pragma unroll
  for (int e = 1; e < NEXP; e++)
    if (l[e] > v1) { v1 = l[e]; i1 = e; }
  int i2 = -1; float v2 = -3.4e38f;
#pragma unroll
  for (int e = 0; e < NEXP; e++)
    if (e != i1 && l[e] > v2) { v2 = l[e]; i2 = e; }
  float ex = expf(v2 - v1);
  float wa = 1.f / (1.f + ex);
  float wb = ex / (1.f + ex);
  idx2[t * 2] = i1; idx2[t * 2 + 1] = i2;
  w2arr[t * 2] = wa; w2arr[t * 2 + 1] = wb;
  atomicAdd(&counts[i1], 1);
  atomicAdd(&counts[i2], 1);
}

__global__ void prefix_kernel(const int* __restrict__ counts, int* __restrict__ offs) {
  if (threadIdx.x == 0 && blockIdx.x == 0) {
    int s = 0;
    for (int e = 0; e < NEXP; e++) { offs[e] = s; s += counts[e]; }
  }
}

__global__ void scatter_kernel(const int* __restrict__ idx2,
                               const int* __restrict__ offs, int* __restrict__ cursors,
                               int* __restrict__ toks, int* __restrict__ posArr) {
  int t = blockIdx.x * blockDim.x + threadIdx.x;
  if (t >= T_TOK) return;
#pragma unroll
  for (int j = 0; j < TOPK; j++) {
    int e = idx2[t * 2 + j];
    int pos = atomicAdd(&cursors[e], 1);
    int s = offs[e] + pos;
    toks[s] = t;
    posArr[t * 2 + j] = s;
  }
}

// ---------------- final combine: y = x + w0*eo[s0] + w1*eo[s1] ----------------
__global__ __launch_bounds__(256) void combine_kernel(
    const float* __restrict__ x, const unsigned short* __restrict__ eo,
    const int* __restrict__ posArr, const float* __restrict__ w2arr,
    float* __restrict__ y) {
  const int t = blockIdx.x;
  const int d = threadIdx.x * 4;
  const int s0 = posArr[t * 2], s1 = posArr[t * 2 + 1];
  const float w0 = w2arr[t * 2], w1 = w2arr[t * 2 + 1];
  float4 xv = *(const float4*)&x[(size_t)t * DDIM + d];
  ushort4 a = *(const ushort4*)&eo[(size_t)s0 * DDIM + d];
  ushort4 b = *(const ushort4*)&eo[(size_t)s1 * DDIM + d];
  float4 o;
  o.x = xv.x + w0 * bf2f(a.x) + w1 * bf2f(b.x);
  o.y = xv.y + w0 * bf2f(a.y) + w1 * bf2f(b.y);
  o.z = xv.z + w0 * bf2f(a.z) + w1 * bf2f(b.z);
  o.w = xv.w + w0 * bf2f(a.w) + w1 * bf2f(b.w);
  *(float4*)&y[(size_t)t * DDIM + d] = o;
}

// ---------------- launch ----------------
extern "C" void kernel_launch(void* const* d_in, const int* in_sizes, int n_in,
                              void* d_out, int out_size, void* d_ws, size_t ws_size,
                              hipStream_t stream) {
  (void)in_sizes; (void)n_in; (void)out_size; (void)ws_size;
  const float* x   = (const float*)d_in[0];
  const float* rw1 = (const float*)d_in[1];
  const float* rb1 = (const float*)d_in[2];
  const float* rw2 = (const float*)d_in[3];
  const float* rb2 = (const float*)d_in[4];
  const float* ew1 = (const float*)d_in[5];
  const float* eb1 = (const float*)d_in[6];
  const float* ew2 = (const float*)d_in[7];
  const float* eb2 = (const float*)d_in[8];
  float* y = (float*)d_out;

  char* ws = (char*)d_ws;
  size_t o = 0;
  auto alloc = [&](size_t bytes) {
    size_t r = o;
    o += (bytes + 255) & ~(size_t)255;
    return r;
  };
  unsigned short* xaug  = (unsigned short*)(ws + alloc((size_t)T_TOK * KAUG * 2));
  unsigned short* waug  = (unsigned short*)(ws + alloc((size_t)DDIM * KAUG * 2));
  unsigned short* ew1t  = (unsigned short*)(ws + alloc((size_t)NEXP * HDIM * DDIM * 2));
  unsigned short* ew2t  = (unsigned short*)(ws + alloc((size_t)NEXP * DDIM * HDIM * 2));
  float*          rh    = (float*)(ws + alloc((size_t)T_TOK * DDIM * 4));
  float*          logits= (float*)(ws + alloc((size_t)T_TOK * NEXP * 4));
  int*            idx2  = (int*)(ws + alloc((size_t)T_TOK * 2 * 4));
  float*          w2    = (float*)(ws + alloc((size_t)T_TOK * 2 * 4));
  int*            toks  = (int*)(ws + alloc((size_t)T_TOK * TOPK * 4));
  int*            posArr= (int*)(ws + alloc((size_t)T_TOK * TOPK * 4));
  int*            counts= (int*)(ws + alloc(256));
  int*            cursors=(int*)(ws + alloc(256));
  int*            offs  = (int*)(ws + alloc(256));
  unsigned short* ehb   = (unsigned short*)(ws + alloc((size_t)T_TOK * TOPK * HDIM * 2));
  unsigned short* eo    = (unsigned short*)(ws + alloc((size_t)T_TOK * TOPK * DDIM * 2));

  constexpr int LDS_SZ = 65536;   // 2 bufs x (A 16K + B 16K) -> 2 blocks/CU
  static bool s_attr = false;
  if (!s_attr) {
    (void)hipFuncSetAttribute((const void*)gemm_s<0>,
                              hipFuncAttributeMaxDynamicSharedMemorySize, LDS_SZ);
    (void)hipFuncSetAttribute((const void*)gemm_s<1>,
                              hipFuncAttributeMaxDynamicSharedMemorySize, LDS_SZ);
    (void)hipFuncSetAttribute((const void*)gemm_s<2>,
                              hipFuncAttributeMaxDynamicSharedMemorySize, LDS_SZ);
    s_attr = true;
  }

  zero_small_kernel<<<1, 64, 0, stream>>>(counts, cursors);

  const int n4 = T_TOK * DDIM / 4;
  split_x_kernel<<<(n4 + 255) / 256, 256, 0, stream>>>(x, xaug, n4);
  split_w_kernel<<<dim3(DDIM / 32, DDIM / 32), 256, 0, stream>>>(rw1, waug);
  transpose_conv_kernel<<<dim3(HDIM / 32, DDIM / 32, NEXP), 256, 0, stream>>>(ew1, ew1t, DDIM, HDIM);
  transpose_conv_kernel<<<dim3(DDIM / 32, HDIM / 32, NEXP), 256, 0, stream>>>(ew2, ew2t, HDIM, DDIM);

  // router layer 1 (split-bf16, K=3072, NT=48): rh = silu(x @ rw1 + rb1)
  // 128x128 tiles: numE=1, nTiles=8, mCap=64 -> grid 512 (2 blocks/CU)
  gemm_s<0><<<512, 256, LDS_SZ, stream>>>(
      xaug, waug, rb1, rh, nullptr, nullptr, nullptr, nullptr,
      DDIM, KAUG, KAUG, 1, 8, 64);
  router2_kernel<<<T_TOK / 4, 256, 0, stream>>>(rh, rw2, rb2, logits);
  topk_kernel<<<T_TOK / 256, 256, 0, stream>>>(logits, idx2, w2, counts);
  prefix_kernel<<<1, 64, 0, stream>>>(counts, offs);
  scatter_kernel<<<T_TOK / 256, 256, 0, stream>>>(idx2, offs, cursors, toks, posArr);

  // expert layer 1: ehb = silu(gather(xaug.hi) @ ew1[e] + eb1[e])  (bf16)
  // NT=16: numE=8 (XCD), nTiles=16, mCap=16 -> grid 2048 (8 blocks/CU deep)
  gemm_s<1><<<8 * 16 * 16, 256, LDS_SZ, stream>>>(
      xaug, ew1t, eb1, nullptr, ehb, toks, offs, counts,
      HDIM, DDIM, KAUG, NEXP, 16, 16);
  // expert layer 2: eo = ehb @ ew2[e] + eb2[e]  (bf16, packed; weights in combine)
  // NT=32: numE=8, nTiles=8, mCap=16 -> grid 1024 (4 blocks/CU deep)
  gemm_s<2><<<8 * 8 * 16, 256, LDS_SZ, stream>>>(
      ehb, ew2t, eb2, nullptr, eo, nullptr, offs, counts,
      DDIM, HDIM, HDIM, NEXP, 8, 16);
  // y = x + w0*eo[s0] + w1*eo[s1]
  combine_kernel<<<T_TOK, 256, 0, stream>>>(x, eo, posArr, w2, y);
}